// Round 15
// baseline (298.221 us; speedup 1.0000x reference)
//
#include <hip/hip_runtime.h>
#include <cstdint>
#include <cstddef>

#define NN 50000            // nodes
#define NNP 50176           // padded rows (GEMM tile overreach stays in-bounds)
#define NE 800000           // edges (before self loops)
#define NT (NE + NN)        // edges incl self loops
#define NG 64               // graphs
#define BN_EPS 1e-5f
#define DEG_SCALE 65536.0f  // fixed-point scale for packed weighted degree
#define SCB 196             // scan blocks (196*256 = 50176 >= NN)
#define MG 391              // GEMM grid.x = ceil(NN/128)
#define CVB 3125            // cvt blocks (NN*128/8/256)
#define PREPB (CVB + 296)   // prep blocks (cvt + weight transposes)
#define EGRID ((NT + 255) / 256)
#define SP128 3125          // spmm grid, F=128 (16 nodes/block)
#define SP64  1563          // spmm grid, F=64
#define SP32  782           // spmm grid, F=32

typedef unsigned int u32;
typedef unsigned short u16;
typedef unsigned long long u64;

using short8 = __attribute__((ext_vector_type(8))) short;  // 8 bf16 (4 VGPRs)
using f32x4  = __attribute__((ext_vector_type(4))) float;

__device__ __forceinline__ float bf_lo(u32 u) { return __builtin_bit_cast(float, u << 16); }
__device__ __forceinline__ float bf_hi(u32 u) { return __builtin_bit_cast(float, u & 0xffff0000u); }
__device__ __forceinline__ u32 f2bf(float f) {           // RNE float->bf16
    u32 u = __builtin_bit_cast(u32, f);
    return (u + 0x7fffu + ((u >> 16) & 1u)) >> 16;
}
__device__ __forceinline__ u32 pack2(float a, float b) { return f2bf(a) | (f2bf(b) << 16); }

__device__ __forceinline__ void gload16(const void* g, void* lds) {
    __builtin_amdgcn_global_load_lds((const __attribute__((address_space(1))) u32*)g,
                                     (__attribute__((address_space(3))) u32*)lds, 16, 0, 0);
}

__device__ __forceinline__ int ld_idx(const int* __restrict__ p, long i, int is64) {
    return is64 ? p[2 * i] : p[i];
}
__device__ __forceinline__ int detect64(const int* __restrict__ ei) {
    return (ei[1] == 0 && ei[3] == 0 && ei[5] == 0 && ei[7] == 0) ? 1 : 0;
}

// ---------------------------------------------------------------------------
// merged: deg (blocks [0,EGRID), atomic latency-bound, starts first) +
// prep (rest: x fp32->bf16 + weight transposes, streaming BW-bound).
__global__ void k_deg_prep(const int* __restrict__ ei, const float* __restrict__ ew,
                           u64* __restrict__ cnt64, u32* __restrict__ ord,
                           const float* __restrict__ x, u16* __restrict__ xb,
                           const float* __restrict__ W1, const float* __restrict__ W2,
                           const float* __restrict__ W3, const float* __restrict__ W4,
                           u16* __restrict__ wt1, u16* __restrict__ wt2,
                           u16* __restrict__ wt3, u16* __restrict__ wt4) {
    if (blockIdx.x < EGRID) {
        const int i = blockIdx.x * 256 + threadIdx.x;
        if (i >= NT) return;
        const int is64 = detect64(ei);
        int d; float w;
        if (i < NE) { d = ld_idx(ei, (long)NE + i, is64); w = ew[i]; }
        else        { d = i - NE;                          w = 1.0f;  }
        const u64 v = ((u64)1 << 40) | (u64)__float2uint_rn(w * DEG_SCALE);
        const u64 old = atomicAdd(&cnt64[d], v);
        ord[i] = (u32)(old >> 40);
        return;
    }
    const int pb = blockIdx.x - EGRID;
    if (pb < CVB) {
        const size_t i = ((size_t)pb * 256 + threadIdx.x) * 8;
        const float4 a = *(const float4*)(x + i);
        const float4 b = *(const float4*)(x + i + 4);
        uint4 o;
        o.x = pack2(a.x, a.y); o.y = pack2(a.z, a.w);
        o.z = pack2(b.x, b.y); o.w = pack2(b.z, b.w);
        *(uint4*)(xb + i) = o;
        return;
    }
    int i = (pb - CVB) * 256 + threadIdx.x;
    const float* W; u16* Wt; int Kd, Nd;
    if (i < 32768)      { W = W1; Wt = wt1; Kd = 128; Nd = 256; }
    else if (i < 65536) { W = W2; Wt = wt2; Kd = 256; Nd = 128; i -= 32768; }
    else if (i < 73728) { W = W3; Wt = wt3; Kd = 128; Nd = 64;  i -= 65536; }
    else if (i < 75776) { W = W4; Wt = wt4; Kd = 64;  Nd = 32;  i -= 73728; }
    else return;
    const int k = i / Nd, n = i % Nd;
    Wt[(size_t)n * Kd + k] = (u16)f2bf(W[i]);
}

// ---------------------------------------------------------------------------
// merged scan (A + barrier + C + graph bounds), one launch.
// 196 blocks — all co-resident on 256 CUs, so the publish/spin barrier is safe.
// flag lives in the zeroed workspace region (deterministic across graph replays).
__global__ void k_scan(const u64* __restrict__ cnt64, int* __restrict__ bsum,
                       int* __restrict__ flag, float* __restrict__ dis,
                       int* __restrict__ rowptr, const int* __restrict__ ei,
                       const int* __restrict__ batch, int* __restrict__ gstart) {
    const int tid = threadIdx.x;
    const int bid = blockIdx.x;
    const int lane = tid & 63;
    const int wid = tid >> 6;
    const int idx = bid * 256 + tid;

    // phase A: chunk sum + dis
    u64 packed = 0;
    if (idx < NN) {
        packed = cnt64[idx];
        const float deg = (float)(packed & (((u64)1 << 40) - 1)) * (1.0f / DEG_SCALE);
        dis[idx] = deg > 0.0f ? rsqrtf(deg) : 0.0f;
    }
    const int c = (int)(packed >> 40);
    int v = c;
    #pragma unroll
    for (int off = 32; off > 0; off >>= 1) v += __shfl_down(v, off, 64);
    __shared__ int wsum[4];
    if (lane == 0) wsum[wid] = v;
    __syncthreads();
    if (tid == 0) {
        bsum[bid] = wsum[0] + wsum[1] + wsum[2] + wsum[3];
        __threadfence();
        atomicAdd(flag, 1);
    }
    // graph bounds in block 0 (independent of barrier; hides spin latency)
    if (bid == 0 && tid <= NG) {
        const int is64 = detect64(ei);
        int lo = 0, hi = NN;
        while (lo < hi) {
            const int mid = (lo + hi) >> 1;
            if (ld_idx(batch, mid, is64) < tid) lo = mid + 1; else hi = mid;
        }
        gstart[tid] = lo;
    }
    // barrier: wait for all 196 block sums
    if (tid == 0) {
        while (atomicAdd(flag, 0) < SCB) {}
    }
    __syncthreads();

    // phase C: prefix over bsum + local exclusive scan -> rowptr
    __shared__ int wv[4], wtt[4], we[4];
    __shared__ int s_base, s_total;
    int pv = 0, pt = 0;
    if (tid < SCB) { const int b = bsum[tid]; pt = b; if (tid < bid) pv = b; }
    #pragma unroll
    for (int off = 32; off > 0; off >>= 1) {
        pv += __shfl_down(pv, off, 64);
        pt += __shfl_down(pt, off, 64);
    }
    if (lane == 0) { wv[wid] = pv; wtt[wid] = pt; }
    __syncthreads();
    if (tid == 0) {
        s_base  = wv[0] + wv[1] + wv[2] + wv[3];
        s_total = wtt[0] + wtt[1] + wtt[2] + wtt[3];
    }
    __syncthreads();
    int s = c;
    #pragma unroll
    for (int off = 1; off < 64; off <<= 1) {
        int t = __shfl_up(s, off, 64);
        if (lane >= off) s += t;
    }
    if (lane == 63) we[wid] = s;
    __syncthreads();
    int base = s_base;
    #pragma unroll
    for (int w = 0; w < 4; ++w) { if (w < wid) base += we[w]; }
    if (idx < NN) rowptr[idx] = base + s - c;
    if (bid == SCB - 1 && tid == 0) rowptr[NN] = s_total;
}

// scatter edges into CSR (by dst): NO atomics — pos = rowptr[d] + ord[i].
__global__ void k_csr2(const int* __restrict__ ei, const float* __restrict__ ew,
                       const float* __restrict__ dis, const int* __restrict__ rowptr,
                       const u32* __restrict__ ord, u64* __restrict__ edges) {
    const int is64 = detect64(ei);
    int i = blockIdx.x * 256 + threadIdx.x;
    const int stride = gridDim.x * 256;
    for (; i < NT; i += stride) {
        int s, d; float w;
        if (i < NE) { s = ld_idx(ei, i, is64); d = ld_idx(ei, (long)NE + i, is64); w = ew[i]; }
        else        { s = d = i - NE;          w = 1.0f;  }
        const int pos = rowptr[d] + (int)ord[i];
        const float nv = dis[s] * w * dis[d];
        edges[pos] = (u64)(u32)s | ((u64)__builtin_bit_cast(u32, nv) << 32);
    }
}

// ---------------------------------------------------------------------------
// SpMM bf16, 8x unrolled edge loop (8 independent gathers in flight);
// optional fused BN-stats epilogue, TRANSPOSED partials P[slot*NP + block].
#define ACC8(XV, V)                                                     \
    a[0] += (V) * bf_lo((XV).x); a[1] += (V) * bf_hi((XV).x);           \
    a[2] += (V) * bf_lo((XV).y); a[3] += (V) * bf_hi((XV).y);           \
    a[4] += (V) * bf_lo((XV).z); a[5] += (V) * bf_hi((XV).z);           \
    a[6] += (V) * bf_lo((XV).w); a[7] += (V) * bf_hi((XV).w);

template <int F, bool STATS, int NP>
__global__ void k_spmm_bf(const int* __restrict__ rowptr, const u64* __restrict__ edges,
                          const u16* __restrict__ x, u16* __restrict__ out,
                          float* __restrict__ P) {
    constexpr int L = F / 8;
    constexpr int NPB = 256 / L;
    const int node = blockIdx.x * NPB + threadIdx.x / L;
    const int q = threadIdx.x % L;
    float a[8] = {};
    if (node < NN) {
        const int beg = rowptr[node], end = rowptr[node + 1];
        int e = beg;
        const int e8 = beg + ((end - beg) & ~7);
        for (; e < e8; e += 8) {
            u64 ev[8];
            #pragma unroll
            for (int j = 0; j < 8; ++j) ev[j] = edges[e + j];
            uint4 xv[8];
            #pragma unroll
            for (int j = 0; j < 8; ++j)
                xv[j] = *(const uint4*)(x + (size_t)(u32)ev[j] * F + q * 8);
            #pragma unroll
            for (int j = 0; j < 8; ++j) {
                const float v = __builtin_bit_cast(float, (u32)(ev[j] >> 32));
                ACC8(xv[j], v)
            }
        }
        const int e4 = beg + ((end - beg) & ~3);
        if (e < e4) {
            u64 ev[4];
            #pragma unroll
            for (int j = 0; j < 4; ++j) ev[j] = edges[e + j];
            uint4 xv[4];
            #pragma unroll
            for (int j = 0; j < 4; ++j)
                xv[j] = *(const uint4*)(x + (size_t)(u32)ev[j] * F + q * 8);
            #pragma unroll
            for (int j = 0; j < 4; ++j) {
                const float v = __builtin_bit_cast(float, (u32)(ev[j] >> 32));
                ACC8(xv[j], v)
            }
            e = e4;
        }
        for (; e < end; ++e) {
            const u64 ev = edges[e];
            const float v = __builtin_bit_cast(float, (u32)(ev >> 32));
            const uint4 xv = *(const uint4*)(x + (size_t)(u32)ev * F + q * 8);
            ACC8(xv, v)
        }
        uint4 o;
        o.x = pack2(a[0], a[1]); o.y = pack2(a[2], a[3]);
        o.z = pack2(a[4], a[5]); o.w = pack2(a[6], a[7]);
        *(uint4*)(out + (size_t)node * F + q * 8) = o;
    }
    if constexpr (STATS) {
        float sj[8], qj[8];
        #pragma unroll
        for (int j = 0; j < 8; ++j) { sj[j] = a[j]; qj[j] = a[j] * a[j]; }
        #pragma unroll
        for (int m = L; m < 64; m <<= 1) {
            #pragma unroll
            for (int j = 0; j < 8; ++j) {
                sj[j] += __shfl_xor(sj[j], m, 64);
                qj[j] += __shfl_xor(qj[j], m, 64);
            }
        }
        const int w = threadIdx.x >> 6;
        const int lane = threadIdx.x & 63;
        __shared__ float red[4][2][F];
        if (lane < L) {
            #pragma unroll
            for (int j = 0; j < 8; ++j) {
                red[w][0][q * 8 + j] = sj[j];
                red[w][1][q * 8 + j] = qj[j];
            }
        }
        __syncthreads();
        for (int i = threadIdx.x; i < 2 * F; i += 256) {
            const int k = i / F, c = i % F;
            P[(size_t)i * NP + blockIdx.x] =
                red[0][k][c] + red[1][k][c] + red[2][k][c] + red[3][k][c];
        }
    }
}

// parallel partial reduce -> fused BN affine coeffs. one block per column.
template <int F, int NP>
__global__ void k_red_par(const float* __restrict__ P, const float* __restrict__ g,
                          const float* __restrict__ be, float* __restrict__ ac) {
    const int f = blockIdx.x;
    const int tid = threadIdx.x;
    float sa = 0.0f, sq = 0.0f;
    for (int b = tid; b < NP; b += 256) {
        sa += P[(size_t)f * NP + b];
        sq += P[(size_t)(F + f) * NP + b];
    }
    #pragma unroll
    for (int off = 32; off > 0; off >>= 1) {
        sa += __shfl_down(sa, off, 64);
        sq += __shfl_down(sq, off, 64);
    }
    __shared__ float ws[4][2];
    if ((tid & 63) == 0) { ws[tid >> 6][0] = sa; ws[tid >> 6][1] = sq; }
    __syncthreads();
    if (tid == 0) {
        sa = ws[0][0] + ws[1][0] + ws[2][0] + ws[3][0];
        sq = ws[0][1] + ws[1][1] + ws[2][1] + ws[3][1];
        const float mu  = sa * (1.0f / NN);
        const float var = sq * (1.0f / NN) - mu * mu;
        const float a = g[f] * rsqrtf(var + BN_EPS);
        ac[f]     = a;
        ac[F + f] = be[f] - mu * a;
    }
}

// GEMM1 partial reduce: slots = by*256 + kind*128 + cl, NP = MG. grid 256.
__global__ void k_red_g1(const float* __restrict__ P, const float* __restrict__ g,
                         const float* __restrict__ be, float* __restrict__ ac) {
    const int c = blockIdx.x;            // global column 0..255
    const int by = c >> 7, cl = c & 127;
    const int slot_s = by * 256 + cl;
    const int slot_q = by * 256 + 128 + cl;
    const int tid = threadIdx.x;
    float sa = 0.0f, sq = 0.0f;
    for (int b = tid; b < MG; b += 256) {
        sa += P[(size_t)slot_s * MG + b];
        sq += P[(size_t)slot_q * MG + b];
    }
    #pragma unroll
    for (int off = 32; off > 0; off >>= 1) {
        sa += __shfl_down(sa, off, 64);
        sq += __shfl_down(sq, off, 64);
    }
    __shared__ float ws[4][2];
    if ((tid & 63) == 0) { ws[tid >> 6][0] = sa; ws[tid >> 6][1] = sq; }
    __syncthreads();
    if (tid == 0) {
        sa = ws[0][0] + ws[1][0] + ws[2][0] + ws[3][0];
        sq = ws[0][1] + ws[1][1] + ws[2][1] + ws[3][1];
        const float mu  = sa * (1.0f / NN);
        const float var = sq * (1.0f / NN) - mu * mu;
        const float a = g[c] * rsqrtf(var + BN_EPS);
        ac[c]       = a;
        ac[256 + c] = be[c] - mu * a;
    }
}

// ---------------------------------------------------------------------------
// bf16 MFMA GEMM: C[M,N] = A[M,K] @ Wt[N,K]^T. Whole Wt tile [BN][K] in LDS.
// BNIN: fused BN affine+ReLU on A during register staging.
// STATS: emit transposed per-block column sum/sumsq partials of fp32 acc.
template <int K, int BN, bool BNIN, bool STATS>
__global__ void k_gemm_bf(const u16* __restrict__ A, const u16* __restrict__ Wt,
                          u16* __restrict__ C, const float* __restrict__ acIn,
                          float* __restrict__ P, int M, int N) {
    constexpr int KS = K / 8;        // 16B slots per Wt row
    constexpr int CT = BN / 16;      // col tiles per block
    constexpr int CG = (CT >= 4) ? 4 : CT;   // col tiles per chunk
    __shared__ alignas(16) u16 sW[BN * K];
    __shared__ alignas(16) u16 sA[2][128 * 32];
    const int tid  = threadIdx.x;
    const int lane = tid & 63;
    const int w    = tid >> 6;
    const int m0 = blockIdx.x * 128;
    const int n0 = blockIdx.y * BN;

    // stage whole Wt tile [BN][K]: phys slot s holds logical slot s^(row&7)
    #pragma unroll
    for (int i = 0; i < (BN * KS) / 256; ++i) {
        const int u = i * 256 + tid;
        const int r = u / KS;
        const int s = u % KS;
        const int ls = s ^ (r & 7);
        gload16(Wt + (size_t)(n0 + r) * K + ls * 8,
                (char*)sW + (i * 256 + w * 64) * 16);
    }
    // stage A chunk [128][32]: phys slot s holds logical slot s^((row>>1)&3)
    auto stageA = [&](int buf, int kt) {
        #pragma unroll
        for (int i = 0; i < 2; ++i) {
            const int u = i * 256 + tid;
            const int r = u >> 2;
            const int s = u & 3;
            const int ls = s ^ ((r >> 1) & 3);
            const int f0 = kt + ls * 8;
            if constexpr (!BNIN) {
                gload16(A + (size_t)(m0 + r) * K + f0,
                        (char*)&sA[buf][0] + (i * 256 + w * 64) * 16);
            } else {
                const uint4 v = *(const uint4*)(A + (size_t)(m0 + r) * K + f0);
                const float4 ma = *(const float4*)(acIn + f0);
                const float4 mb = *(const float4*)(acIn + f0 + 4);
                const float4 ba = *(const float4*)(acIn + K + f0);
                const float4 bb = *(const float4*)(acIn + K + f0 + 4);
                const float y0 = fmaxf(bf_lo(v.x) * ma.x + ba.x, 0.f);
                const float y1 = fmaxf(bf_hi(v.x) * ma.y + ba.y, 0.f);
                const float y2 = fmaxf(bf_lo(v.y) * ma.z + ba.z, 0.f);
                const float y3 = fmaxf(bf_hi(v.y) * ma.w + ba.w, 0.f);
                const float y4 = fmaxf(bf_lo(v.z) * mb.x + bb.x, 0.f);
                const float y5 = fmaxf(bf_hi(v.z) * mb.y + bb.y, 0.f);
                const float y6 = fmaxf(bf_lo(v.w) * mb.z + bb.z, 0.f);
                const float y7 = fmaxf(bf_hi(v.w) * mb.w + bb.w, 0.f);
                uint4 o;
                o.x = pack2(y0, y1); o.y = pack2(y2, y3);
                o.z = pack2(y4, y5); o.w = pack2(y6, y7);
                *(uint4*)((char*)&sA[buf][0] + u * 16) = o;
            }
        }
    };
    stageA(0, 0);
    __syncthreads();

    f32x4 acc[2][CT] = {};
    const int rl  = lane & 15;
    const int k16 = lane >> 4;
    for (int ki = 0; ki < K / 32; ++ki) {
        if (ki + 1 < K / 32) stageA((ki + 1) & 1, (ki + 1) * 32);
        short8 af[2];
        #pragma unroll
        for (int rt = 0; rt < 2; ++rt) {
            const int row = w * 32 + rt * 16 + rl;
            const int p = k16 ^ ((row >> 1) & 3);
            af[rt] = *(const short8*)((const char*)&sA[ki & 1][0] + row * 64 + p * 16);
        }
        #pragma unroll
        for (int cg = 0; cg < CT / CG; ++cg) {
            short8 bfr[CG];
            #pragma unroll
            for (int j = 0; j < CG; ++j) {
                const int c = (cg * CG + j) * 16 + rl;
                const int p = (ki * 4 + k16) ^ (c & 7);
                bfr[j] = *(const short8*)((const char*)sW + c * (K * 2) + p * 16);
            }
            #pragma unroll
            for (int rt = 0; rt < 2; ++rt)
                #pragma unroll
                for (int j = 0; j < CG; ++j)
                    acc[rt][cg * CG + j] = __builtin_amdgcn_mfma_f32_16x16x32_bf16(
                        af[rt], bfr[j], acc[rt][cg * CG + j], 0, 0, 0);
        }
        __syncthreads();
    }

    // D[(lane>>4)*4 + r][lane&15] per 16x16 tile
    #pragma unroll
    for (int rt = 0; rt < 2; ++rt) {
        #pragma unroll
        for (int r = 0; r < 4; ++r) {
            const int row = m0 + w * 32 + rt * 16 + k16 * 4 + r;
            if (row < M) {
                #pragma unroll
                for (int ct = 0; ct < CT; ++ct)
                    C[(size_t)row * N + n0 + ct * 16 + rl] = (u16)f2bf(acc[rt][ct][r]);
            }
        }
    }

    if constexpr (STATS) {
        __shared__ float red[4][2][BN];
        #pragma unroll
        for (int ct = 0; ct < CT; ++ct) {
            float sc = 0.f, ssc = 0.f;
            #pragma unroll
            for (int rt = 0; rt < 2; ++rt) {
                #pragma unroll
                for (int r = 0; r < 4; ++r) {
                    const int row = m0 + w * 32 + rt * 16 + k16 * 4 + r;
                    if (row < NN) {
                        const float v = acc[rt][ct][r];
                        sc += v; ssc += v * v;
                    }
                }
            }
            sc  += __shfl_xor(sc, 16, 64);  ssc += __shfl_xor(ssc, 16, 64);
            sc  += __shfl_xor(sc, 32, 64);  ssc += __shfl_xor(ssc, 32, 64);
            if (lane < 16) { red[w][0][ct * 16 + lane] = sc; red[w][1][ct * 16 + lane] = ssc; }
        }
        __syncthreads();
        for (int i = tid; i < 2 * BN; i += 256) {
            const int kind = i / BN, cl = i % BN;
            const int slot = blockIdx.y * 2 * BN + kind * BN + cl;
            P[(size_t)slot * gridDim.x + blockIdx.x] =
                red[0][kind][cl] + red[1][kind][cl] + red[2][kind][cl] + red[3][kind][cl];
        }
    }
}

// ---------------------------------------------------------------------------
// fused BN4 + mean-pool + linear head + sigmoid (bf16 input)
__global__ void k_pool_bf(const u16* __restrict__ h, const int* __restrict__ gstart,
                          const float* __restrict__ ac,
                          const float* __restrict__ Wl, const float* __restrict__ bl,
                          float* __restrict__ out) {
    const int g = blockIdx.x;
    const int s = gstart[g], e = gstart[g + 1];
    const int f = threadIdx.x & 31, c = threadIdx.x >> 5;
    const float m = ac[f], b = ac[32 + f];
    float acc = 0.0f;
    for (int r = s + c; r < e; r += 8)
        acc += fmaxf(bf_lo((u32)h[(size_t)r * 32 + f]) * m + b, 0.f);
    __shared__ float red[8][32];
    red[c][f] = acc;
    __syncthreads();
    if (threadIdx.x < 32) {
        float t = 0.0f;
        #pragma unroll
        for (int i = 0; i < 8; ++i) t += red[i][f];
        float cntf = (float)(e - s);
        cntf = cntf > 1.0f ? cntf : 1.0f;
        float p = (t / cntf) * Wl[f];
        #pragma unroll
        for (int off = 16; off > 0; off >>= 1) p += __shfl_down(p, off, 32);
        if (f == 0) out[g] = 1.0f / (1.0f + expf(-(p + bl[0])));
    }
}

// ---------------------------------------------------------------------------
extern "C" void kernel_launch(void* const* d_in, const int* in_sizes, int n_in,
                              void* d_out, int out_size, void* d_ws, size_t ws_size,
                              hipStream_t stream) {
    const float* x     = (const float*)d_in[0];
    const int*   ei    = (const int*)d_in[1];
    const float* ew    = (const float*)d_in[2];
    const int*   batch = (const int*)d_in[3];
    const float* W1 = (const float*)d_in[4];
    const float* g1 = (const float*)d_in[6];
    const float* be1 = (const float*)d_in[7];
    const float* W2 = (const float*)d_in[8];
    const float* g2 = (const float*)d_in[10];
    const float* be2 = (const float*)d_in[11];
    const float* W3 = (const float*)d_in[12];
    const float* g3 = (const float*)d_in[14];
    const float* be3 = (const float*)d_in[15];
    const float* W4 = (const float*)d_in[16];
    const float* g4 = (const float*)d_in[18];
    const float* be4 = (const float*)d_in[19];
    const float* Wl = (const float*)d_in[20];
    const float* bl = (const float*)d_in[21];
    float* out = (float*)d_out;

    char* ws = (char*)d_ws;
    size_t off = 0;
    auto alloc = [&](size_t bytes) -> void* {
        void* p = ws + off;
        off += (bytes + 255) & ~(size_t)255;
        return p;
    };
    // zeroed region first (one memset): cnt64 + scan barrier flag
    u64* cnt64 = (u64*)alloc((size_t)NN * 8);
    int* flag  = (int*)alloc(256);
    const size_t zero_bytes = off;
    // non-zeroed
    float* ac     = (float*)alloc(512 * 4);
    float* P      = (float*)alloc((size_t)256 * SP128 * 4);   // BN partials (max)
    int*   gstart = (int*)  alloc((NG + 1) * 4);
    int*   rowptr = (int*)  alloc((size_t)(NN + 1) * 4);
    int*   bsum   = (int*)  alloc((size_t)SCB * 4);
    float* dis    = (float*)alloc((size_t)NN * 4);
    u32*   ord    = (u32*)  alloc((size_t)NT * 4);
    u64*   edges  = (u64*)  alloc((size_t)NT * 8);
    u16*   xb     = (u16*)  alloc((size_t)NNP * 128 * 2);
    u16*   wt1    = (u16*)  alloc((size_t)256 * 128 * 2);
    u16*   wt2    = (u16*)  alloc((size_t)128 * 256 * 2);
    u16*   wt3    = (u16*)  alloc((size_t)64 * 128 * 2);
    u16*   wt4    = (u16*)  alloc((size_t)32 * 64 * 2);
    u16*   bufA   = (u16*)  alloc((size_t)NNP * 256 * 2);
    u16*   bufB   = (u16*)  alloc((size_t)NNP * 256 * 2);

    hipMemsetAsync(d_ws, 0, zero_bytes, stream);

    // graph build + input prep (merged, overlapping; deg blocks first)
    k_deg_prep<<<EGRID + PREPB, 256, 0, stream>>>(ei, ew, cnt64, ord, x, xb,
                                                  W1, W2, W3, W4, wt1, wt2, wt3, wt4);
    k_scan<<<SCB, 256, 0, stream>>>(cnt64, bsum, flag, dis, rowptr, ei, batch, gstart);
    k_csr2<<<EGRID, 256, 0, stream>>>(ei, ew, dis, rowptr, ord, edges);

    // ---- layer 1: aggregate(128) -> GEMM 128->256 (+stats) -> red
    k_spmm_bf<128, false, SP128><<<SP128, 256, 0, stream>>>(rowptr, edges, xb, bufA, P);
    k_gemm_bf<128, 128, false, true><<<dim3(MG, 2), 256, 0, stream>>>(bufA, wt1, bufB, ac, P, NN, 256);
    k_red_g1<<<256, 256, 0, stream>>>(P, g1, be1, ac);

    // ---- layer 2: GEMM 256->128 (BN1 in) -> aggregate(128) (+stats) -> red
    k_gemm_bf<256, 64, true, false><<<dim3(MG, 2), 256, 0, stream>>>(bufB, wt2, bufA, ac, P, NN, 128);
    k_spmm_bf<128, true, SP128><<<SP128, 256, 0, stream>>>(rowptr, edges, bufA, bufB, P);
    k_red_par<128, SP128><<<128, 256, 0, stream>>>(P, g2, be2, ac);

    // ---- layer 3: GEMM 128->64 (BN2 in) -> aggregate(64) (+stats) -> red
    k_gemm_bf<128, 64, true, false><<<dim3(MG, 1), 256, 0, stream>>>(bufB, wt3, bufA, ac, P, NN, 64);
    k_spmm_bf<64, true, SP64><<<SP64, 256, 0, stream>>>(rowptr, edges, bufA, bufB, P);
    k_red_par<64, SP64><<<64, 256, 0, stream>>>(P, g3, be3, ac);

    // ---- layer 4: GEMM 64->32 (BN3 in) -> aggregate(32) (+stats) -> red
    k_gemm_bf<64, 32, true, false><<<dim3(MG, 1), 256, 0, stream>>>(bufB, wt4, bufA, ac, P, NN, 32);
    k_spmm_bf<32, true, SP32><<<SP32, 256, 0, stream>>>(rowptr, edges, bufA, bufB, P);
    k_red_par<32, SP32><<<32, 256, 0, stream>>>(P, g4, be4, ac);

    // ---- fused BN4 + pool + head
    k_pool_bf<<<NG, 256, 0, stream>>>(bufB, gstart, ac, Wl, bl, out);
}

// Round 16
// 286.296 us; speedup vs baseline: 1.0417x; 1.0417x over previous
//
#include <hip/hip_runtime.h>
#include <cstdint>
#include <cstddef>

#define NN 50000            // nodes
#define NNP 50176           // padded rows (GEMM tile overreach stays in-bounds)
#define NE 800000           // edges (before self loops)
#define NT (NE + NN)        // edges incl self loops
#define NG 64               // graphs
#define BN_EPS 1e-5f
#define DEG_SCALE 65536.0f  // fixed-point scale for packed weighted degree
#define SCB 196             // scan blocks (196*256 = 50176 >= NN)
#define MG 391              // GEMM grid.x = ceil(NN/128)
#define CVB 3125            // cvt blocks (NN*128/8/256)
#define PREPB (CVB + 296)   // prep blocks (cvt + weight transposes)
#define EGRID ((NT + 255) / 256)
#define SP128 3125          // spmm grid, F=128 (16 nodes/block)
#define SP64  1563          // spmm grid, F=64
#define SP32  782           // spmm grid, F=32

typedef unsigned int u32;
typedef unsigned short u16;
typedef unsigned long long u64;

using short8 = __attribute__((ext_vector_type(8))) short;  // 8 bf16 (4 VGPRs)
using f32x4  = __attribute__((ext_vector_type(4))) float;

__device__ __forceinline__ float bf_lo(u32 u) { return __builtin_bit_cast(float, u << 16); }
__device__ __forceinline__ float bf_hi(u32 u) { return __builtin_bit_cast(float, u & 0xffff0000u); }
__device__ __forceinline__ u32 f2bf(float f) {           // RNE float->bf16
    u32 u = __builtin_bit_cast(u32, f);
    return (u + 0x7fffu + ((u >> 16) & 1u)) >> 16;
}
__device__ __forceinline__ u32 pack2(float a, float b) { return f2bf(a) | (f2bf(b) << 16); }

__device__ __forceinline__ void gload16(const void* g, void* lds) {
    __builtin_amdgcn_global_load_lds((const __attribute__((address_space(1))) u32*)g,
                                     (__attribute__((address_space(3))) u32*)lds, 16, 0, 0);
}

__device__ __forceinline__ int ld_idx(const int* __restrict__ p, long i, int is64) {
    return is64 ? p[2 * i] : p[i];
}
__device__ __forceinline__ int detect64(const int* __restrict__ ei) {
    return (ei[1] == 0 && ei[3] == 0 && ei[5] == 0 && ei[7] == 0) ? 1 : 0;
}

// ---------------------------------------------------------------------------
// merged: deg (blocks [0,EGRID), atomic latency-bound, starts first) +
// prep (rest: x fp32->bf16 + weight transposes, streaming BW-bound).
__global__ void k_deg_prep(const int* __restrict__ ei, const float* __restrict__ ew,
                           u64* __restrict__ cnt64, u32* __restrict__ ord,
                           const float* __restrict__ x, u16* __restrict__ xb,
                           const float* __restrict__ W1, const float* __restrict__ W2,
                           const float* __restrict__ W3, const float* __restrict__ W4,
                           u16* __restrict__ wt1, u16* __restrict__ wt2,
                           u16* __restrict__ wt3, u16* __restrict__ wt4) {
    if (blockIdx.x < EGRID) {
        const int i = blockIdx.x * 256 + threadIdx.x;
        if (i >= NT) return;
        const int is64 = detect64(ei);
        int d; float w;
        if (i < NE) { d = ld_idx(ei, (long)NE + i, is64); w = ew[i]; }
        else        { d = i - NE;                          w = 1.0f;  }
        const u64 v = ((u64)1 << 40) | (u64)__float2uint_rn(w * DEG_SCALE);
        const u64 old = atomicAdd(&cnt64[d], v);
        ord[i] = (u32)(old >> 40);
        return;
    }
    const int pb = blockIdx.x - EGRID;
    if (pb < CVB) {
        const size_t i = ((size_t)pb * 256 + threadIdx.x) * 8;
        const float4 a = *(const float4*)(x + i);
        const float4 b = *(const float4*)(x + i + 4);
        uint4 o;
        o.x = pack2(a.x, a.y); o.y = pack2(a.z, a.w);
        o.z = pack2(b.x, b.y); o.w = pack2(b.z, b.w);
        *(uint4*)(xb + i) = o;
        return;
    }
    int i = (pb - CVB) * 256 + threadIdx.x;
    const float* W; u16* Wt; int Kd, Nd;
    if (i < 32768)      { W = W1; Wt = wt1; Kd = 128; Nd = 256; }
    else if (i < 65536) { W = W2; Wt = wt2; Kd = 256; Nd = 128; i -= 32768; }
    else if (i < 73728) { W = W3; Wt = wt3; Kd = 128; Nd = 64;  i -= 65536; }
    else if (i < 75776) { W = W4; Wt = wt4; Kd = 64;  Nd = 32;  i -= 73728; }
    else return;
    const int k = i / Nd, n = i % Nd;
    Wt[(size_t)n * Kd + k] = (u16)f2bf(W[i]);
}

// ---------------------------------------------------------------------------
// scan phase A: per-block chunk sums + dis = deg^-1/2
__global__ void k_scan_a(const u64* __restrict__ cnt64, int* __restrict__ blocksum,
                         float* __restrict__ dis) {
    const int tid = threadIdx.x;
    const int idx = blockIdx.x * 256 + tid;
    u64 packed = 0;
    if (idx < NN) {
        packed = cnt64[idx];
        const float deg = (float)(packed & (((u64)1 << 40) - 1)) * (1.0f / DEG_SCALE);
        dis[idx] = deg > 0.0f ? rsqrtf(deg) : 0.0f;
    }
    int v = (int)(packed >> 40);
    #pragma unroll
    for (int off = 32; off > 0; off >>= 1) v += __shfl_down(v, off, 64);
    __shared__ int wsum[4];
    if ((tid & 63) == 0) wsum[tid >> 6] = v;
    __syncthreads();
    if (tid == 0) blocksum[blockIdx.x] = wsum[0] + wsum[1] + wsum[2] + wsum[3];
}

// scan phase C (merged B + graph bounds): per-block prefix over bsum, local
// exclusive scan -> rowptr; block 0 computes gstart via binary search.
__global__ void k_scan_c(const u64* __restrict__ cnt64, const int* __restrict__ bsum,
                         int* __restrict__ rowptr, const int* __restrict__ ei,
                         const int* __restrict__ batch, int* __restrict__ gstart) {
    const int tid = threadIdx.x;
    const int bid = blockIdx.x;
    const int lane = tid & 63;
    const int wid = tid >> 6;
    __shared__ int wv[4], wtt[4], we[4];
    __shared__ int s_base, s_total;
    int v = 0, vt = 0;
    if (tid < SCB) { const int b = bsum[tid]; vt = b; if (tid < bid) v = b; }
    #pragma unroll
    for (int off = 32; off > 0; off >>= 1) {
        v  += __shfl_down(v, off, 64);
        vt += __shfl_down(vt, off, 64);
    }
    if (lane == 0) { wv[wid] = v; wtt[wid] = vt; }
    __syncthreads();
    if (tid == 0) {
        s_base  = wv[0] + wv[1] + wv[2] + wv[3];
        s_total = wtt[0] + wtt[1] + wtt[2] + wtt[3];
    }
    __syncthreads();
    const int idx = bid * 256 + tid;
    const int c = (idx < NN) ? (int)(cnt64[idx] >> 40) : 0;
    int s = c;
    #pragma unroll
    for (int off = 1; off < 64; off <<= 1) {
        int t = __shfl_up(s, off, 64);
        if (lane >= off) s += t;
    }
    if (lane == 63) we[wid] = s;
    __syncthreads();
    int base = s_base;
    #pragma unroll
    for (int w = 0; w < 4; ++w) { if (w < wid) base += we[w]; }
    if (idx < NN) rowptr[idx] = base + s - c;
    if (bid == SCB - 1 && tid == 0) rowptr[NN] = s_total;
    if (bid == 0 && tid <= NG) {
        const int is64 = detect64(ei);
        int lo = 0, hi = NN;
        while (lo < hi) {
            const int mid = (lo + hi) >> 1;
            if (ld_idx(batch, mid, is64) < tid) lo = mid + 1; else hi = mid;
        }
        gstart[tid] = lo;
    }
}

// scatter edges into CSR (by dst): NO atomics — pos = rowptr[d] + ord[i].
__global__ void k_csr2(const int* __restrict__ ei, const float* __restrict__ ew,
                       const float* __restrict__ dis, const int* __restrict__ rowptr,
                       const u32* __restrict__ ord, u64* __restrict__ edges) {
    const int is64 = detect64(ei);
    int i = blockIdx.x * 256 + threadIdx.x;
    const int stride = gridDim.x * 256;
    for (; i < NT; i += stride) {
        int s, d; float w;
        if (i < NE) { s = ld_idx(ei, i, is64); d = ld_idx(ei, (long)NE + i, is64); w = ew[i]; }
        else        { s = d = i - NE;          w = 1.0f;  }
        const int pos = rowptr[d] + (int)ord[i];
        const float nv = dis[s] * w * dis[d];
        edges[pos] = (u64)(u32)s | ((u64)__builtin_bit_cast(u32, nv) << 32);
    }
}

// ---------------------------------------------------------------------------
// SpMM bf16, 4x unrolled edge loop; optional fused BN-stats epilogue writing
// TRANSPOSED per-block partials P[slot * NP + blockIdx.x] (slot in [0,2F)).
#define ACC8(XV, V)                                                     \
    a[0] += (V) * bf_lo((XV).x); a[1] += (V) * bf_hi((XV).x);           \
    a[2] += (V) * bf_lo((XV).y); a[3] += (V) * bf_hi((XV).y);           \
    a[4] += (V) * bf_lo((XV).z); a[5] += (V) * bf_hi((XV).z);           \
    a[6] += (V) * bf_lo((XV).w); a[7] += (V) * bf_hi((XV).w);

template <int F, bool STATS, int NP>
__global__ void k_spmm_bf(const int* __restrict__ rowptr, const u64* __restrict__ edges,
                          const u16* __restrict__ x, u16* __restrict__ out,
                          float* __restrict__ P) {
    constexpr int L = F / 8;
    constexpr int NPB = 256 / L;
    const int node = blockIdx.x * NPB + threadIdx.x / L;
    const int q = threadIdx.x % L;
    float a[8] = {};
    if (node < NN) {
        const int beg = rowptr[node], end = rowptr[node + 1];
        int e = beg;
        const int e4 = beg + ((end - beg) & ~3);
        for (; e < e4; e += 4) {
            const u64 ev0 = edges[e + 0];
            const u64 ev1 = edges[e + 1];
            const u64 ev2 = edges[e + 2];
            const u64 ev3 = edges[e + 3];
            const uint4 x0 = *(const uint4*)(x + (size_t)(u32)ev0 * F + q * 8);
            const uint4 x1 = *(const uint4*)(x + (size_t)(u32)ev1 * F + q * 8);
            const uint4 x2 = *(const uint4*)(x + (size_t)(u32)ev2 * F + q * 8);
            const uint4 x3 = *(const uint4*)(x + (size_t)(u32)ev3 * F + q * 8);
            const float v0 = __builtin_bit_cast(float, (u32)(ev0 >> 32));
            const float v1 = __builtin_bit_cast(float, (u32)(ev1 >> 32));
            const float v2 = __builtin_bit_cast(float, (u32)(ev2 >> 32));
            const float v3 = __builtin_bit_cast(float, (u32)(ev3 >> 32));
            ACC8(x0, v0) ACC8(x1, v1) ACC8(x2, v2) ACC8(x3, v3)
        }
        for (; e < end; ++e) {
            const u64 ev = edges[e];
            const float v = __builtin_bit_cast(float, (u32)(ev >> 32));
            const uint4 xv = *(const uint4*)(x + (size_t)(u32)ev * F + q * 8);
            ACC8(xv, v)
        }
        uint4 o;
        o.x = pack2(a[0], a[1]); o.y = pack2(a[2], a[3]);
        o.z = pack2(a[4], a[5]); o.w = pack2(a[6], a[7]);
        *(uint4*)(out + (size_t)node * F + q * 8) = o;
    }
    if constexpr (STATS) {
        float sj[8], qj[8];
        #pragma unroll
        for (int j = 0; j < 8; ++j) { sj[j] = a[j]; qj[j] = a[j] * a[j]; }
        #pragma unroll
        for (int m = L; m < 64; m <<= 1) {
            #pragma unroll
            for (int j = 0; j < 8; ++j) {
                sj[j] += __shfl_xor(sj[j], m, 64);
                qj[j] += __shfl_xor(qj[j], m, 64);
            }
        }
        const int w = threadIdx.x >> 6;
        const int lane = threadIdx.x & 63;
        __shared__ float red[4][2][F];
        if (lane < L) {
            #pragma unroll
            for (int j = 0; j < 8; ++j) {
                red[w][0][q * 8 + j] = sj[j];
                red[w][1][q * 8 + j] = qj[j];
            }
        }
        __syncthreads();
        for (int i = threadIdx.x; i < 2 * F; i += 256) {
            const int k = i / F, c = i % F;
            P[(size_t)i * NP + blockIdx.x] =
                red[0][k][c] + red[1][k][c] + red[2][k][c] + red[3][k][c];
        }
    }
}

// parallel partial reduce -> fused BN affine coeffs. one block per column.
template <int F, int NP>
__global__ void k_red_par(const float* __restrict__ P, const float* __restrict__ g,
                          const float* __restrict__ be, float* __restrict__ ac) {
    const int f = blockIdx.x;
    const int tid = threadIdx.x;
    float sa = 0.0f, sq = 0.0f;
    for (int b = tid; b < NP; b += 256) {
        sa += P[(size_t)f * NP + b];
        sq += P[(size_t)(F + f) * NP + b];
    }
    #pragma unroll
    for (int off = 32; off > 0; off >>= 1) {
        sa += __shfl_down(sa, off, 64);
        sq += __shfl_down(sq, off, 64);
    }
    __shared__ float ws[4][2];
    if ((tid & 63) == 0) { ws[tid >> 6][0] = sa; ws[tid >> 6][1] = sq; }
    __syncthreads();
    if (tid == 0) {
        sa = ws[0][0] + ws[1][0] + ws[2][0] + ws[3][0];
        sq = ws[0][1] + ws[1][1] + ws[2][1] + ws[3][1];
        const float mu  = sa * (1.0f / NN);
        const float var = sq * (1.0f / NN) - mu * mu;
        const float a = g[f] * rsqrtf(var + BN_EPS);
        ac[f]     = a;
        ac[F + f] = be[f] - mu * a;
    }
}

// GEMM1 partial reduce: slots = by*256 + kind*128 + cl, NP = MG. grid 256.
__global__ void k_red_g1(const float* __restrict__ P, const float* __restrict__ g,
                         const float* __restrict__ be, float* __restrict__ ac) {
    const int c = blockIdx.x;            // global column 0..255
    const int by = c >> 7, cl = c & 127;
    const int slot_s = by * 256 + cl;
    const int slot_q = by * 256 + 128 + cl;
    const int tid = threadIdx.x;
    float sa = 0.0f, sq = 0.0f;
    for (int b = tid; b < MG; b += 256) {
        sa += P[(size_t)slot_s * MG + b];
        sq += P[(size_t)slot_q * MG + b];
    }
    #pragma unroll
    for (int off = 32; off > 0; off >>= 1) {
        sa += __shfl_down(sa, off, 64);
        sq += __shfl_down(sq, off, 64);
    }
    __shared__ float ws[4][2];
    if ((tid & 63) == 0) { ws[tid >> 6][0] = sa; ws[tid >> 6][1] = sq; }
    __syncthreads();
    if (tid == 0) {
        sa = ws[0][0] + ws[1][0] + ws[2][0] + ws[3][0];
        sq = ws[0][1] + ws[1][1] + ws[2][1] + ws[3][1];
        const float mu  = sa * (1.0f / NN);
        const float var = sq * (1.0f / NN) - mu * mu;
        const float a = g[c] * rsqrtf(var + BN_EPS);
        ac[c]       = a;
        ac[256 + c] = be[c] - mu * a;
    }
}

// ---------------------------------------------------------------------------
// bf16 MFMA GEMM: C[M,N] = A[M,K] @ Wt[N,K]^T. Whole Wt tile [BN][K] in LDS.
// BNIN: fused BN affine+ReLU on A during register staging.
// STATS: emit transposed per-block column sum/sumsq partials of fp32 acc.
template <int K, int BN, bool BNIN, bool STATS>
__global__ void k_gemm_bf(const u16* __restrict__ A, const u16* __restrict__ Wt,
                          u16* __restrict__ C, const float* __restrict__ acIn,
                          float* __restrict__ P, int M, int N) {
    constexpr int KS = K / 8;        // 16B slots per Wt row
    constexpr int CT = BN / 16;      // col tiles per block
    constexpr int CG = (CT >= 4) ? 4 : CT;   // col tiles per chunk
    __shared__ alignas(16) u16 sW[BN * K];
    __shared__ alignas(16) u16 sA[2][128 * 32];
    const int tid  = threadIdx.x;
    const int lane = tid & 63;
    const int w    = tid >> 6;
    const int m0 = blockIdx.x * 128;
    const int n0 = blockIdx.y * BN;

    // stage whole Wt tile [BN][K]: phys slot s holds logical slot s^(row&7)
    #pragma unroll
    for (int i = 0; i < (BN * KS) / 256; ++i) {
        const int u = i * 256 + tid;
        const int r = u / KS;
        const int s = u % KS;
        const int ls = s ^ (r & 7);
        gload16(Wt + (size_t)(n0 + r) * K + ls * 8,
                (char*)sW + (i * 256 + w * 64) * 16);
    }
    // stage A chunk [128][32]: phys slot s holds logical slot s^((row>>1)&3)
    auto stageA = [&](int buf, int kt) {
        #pragma unroll
        for (int i = 0; i < 2; ++i) {
            const int u = i * 256 + tid;
            const int r = u >> 2;
            const int s = u & 3;
            const int ls = s ^ ((r >> 1) & 3);
            const int f0 = kt + ls * 8;
            if constexpr (!BNIN) {
                gload16(A + (size_t)(m0 + r) * K + f0,
                        (char*)&sA[buf][0] + (i * 256 + w * 64) * 16);
            } else {
                const uint4 v = *(const uint4*)(A + (size_t)(m0 + r) * K + f0);
                const float4 ma = *(const float4*)(acIn + f0);
                const float4 mb = *(const float4*)(acIn + f0 + 4);
                const float4 ba = *(const float4*)(acIn + K + f0);
                const float4 bb = *(const float4*)(acIn + K + f0 + 4);
                const float y0 = fmaxf(bf_lo(v.x) * ma.x + ba.x, 0.f);
                const float y1 = fmaxf(bf_hi(v.x) * ma.y + ba.y, 0.f);
                const float y2 = fmaxf(bf_lo(v.y) * ma.z + ba.z, 0.f);
                const float y3 = fmaxf(bf_hi(v.y) * ma.w + ba.w, 0.f);
                const float y4 = fmaxf(bf_lo(v.z) * mb.x + bb.x, 0.f);
                const float y5 = fmaxf(bf_hi(v.z) * mb.y + bb.y, 0.f);
                const float y6 = fmaxf(bf_lo(v.w) * mb.z + bb.z, 0.f);
                const float y7 = fmaxf(bf_hi(v.w) * mb.w + bb.w, 0.f);
                uint4 o;
                o.x = pack2(y0, y1); o.y = pack2(y2, y3);
                o.z = pack2(y4, y5); o.w = pack2(y6, y7);
                *(uint4*)((char*)&sA[buf][0] + u * 16) = o;
            }
        }
    };
    stageA(0, 0);
    __syncthreads();

    f32x4 acc[2][CT] = {};
    const int rl  = lane & 15;
    const int k16 = lane >> 4;
    for (int ki = 0; ki < K / 32; ++ki) {
        if (ki + 1 < K / 32) stageA((ki + 1) & 1, (ki + 1) * 32);
        short8 af[2];
        #pragma unroll
        for (int rt = 0; rt < 2; ++rt) {
            const int row = w * 32 + rt * 16 + rl;
            const int p = k16 ^ ((row >> 1) & 3);
            af[rt] = *(const short8*)((const char*)&sA[ki & 1][0] + row * 64 + p * 16);
        }
        #pragma unroll
        for (int cg = 0; cg < CT / CG; ++cg) {
            short8 bfr[CG];
            #pragma unroll
            for (int j = 0; j < CG; ++j) {
                const int c = (cg * CG + j) * 16 + rl;
                const int p = (ki * 4 + k16) ^ (c & 7);
                bfr[j] = *(const short8*)((const char*)sW + c * (K * 2) + p * 16);
            }
            #pragma unroll
            for (int rt = 0; rt < 2; ++rt)
                #pragma unroll
                for (int j = 0; j < CG; ++j)
                    acc[rt][cg * CG + j] = __builtin_amdgcn_mfma_f32_16x16x32_bf16(
                        af[rt], bfr[j], acc[rt][cg * CG + j], 0, 0, 0);
        }
        __syncthreads();
    }

    // D[(lane>>4)*4 + r][lane&15] per 16x16 tile
    #pragma unroll
    for (int rt = 0; rt < 2; ++rt) {
        #pragma unroll
        for (int r = 0; r < 4; ++r) {
            const int row = m0 + w * 32 + rt * 16 + k16 * 4 + r;
            if (row < M) {
                #pragma unroll
                for (int ct = 0; ct < CT; ++ct)
                    C[(size_t)row * N + n0 + ct * 16 + rl] = (u16)f2bf(acc[rt][ct][r]);
            }
        }
    }

    if constexpr (STATS) {
        __shared__ float red[4][2][BN];
        #pragma unroll
        for (int ct = 0; ct < CT; ++ct) {
            float sc = 0.f, ssc = 0.f;
            #pragma unroll
            for (int rt = 0; rt < 2; ++rt) {
                #pragma unroll
                for (int r = 0; r < 4; ++r) {
                    const int row = m0 + w * 32 + rt * 16 + k16 * 4 + r;
                    if (row < NN) {
                        const float v = acc[rt][ct][r];
                        sc += v; ssc += v * v;
                    }
                }
            }
            sc  += __shfl_xor(sc, 16, 64);  ssc += __shfl_xor(ssc, 16, 64);
            sc  += __shfl_xor(sc, 32, 64);  ssc += __shfl_xor(ssc, 32, 64);
            if (lane < 16) { red[w][0][ct * 16 + lane] = sc; red[w][1][ct * 16 + lane] = ssc; }
        }
        __syncthreads();
        for (int i = tid; i < 2 * BN; i += 256) {
            const int kind = i / BN, cl = i % BN;
            const int slot = blockIdx.y * 2 * BN + kind * BN + cl;
            P[(size_t)slot * gridDim.x + blockIdx.x] =
                red[0][kind][cl] + red[1][kind][cl] + red[2][kind][cl] + red[3][kind][cl];
        }
    }
}

// ---------------------------------------------------------------------------
// fused BN4 + mean-pool + linear head + sigmoid (bf16 input)
__global__ void k_pool_bf(const u16* __restrict__ h, const int* __restrict__ gstart,
                          const float* __restrict__ ac,
                          const float* __restrict__ Wl, const float* __restrict__ bl,
                          float* __restrict__ out) {
    const int g = blockIdx.x;
    const int s = gstart[g], e = gstart[g + 1];
    const int f = threadIdx.x & 31, c = threadIdx.x >> 5;
    const float m = ac[f], b = ac[32 + f];
    float acc = 0.0f;
    for (int r = s + c; r < e; r += 8)
        acc += fmaxf(bf_lo((u32)h[(size_t)r * 32 + f]) * m + b, 0.f);
    __shared__ float red[8][32];
    red[c][f] = acc;
    __syncthreads();
    if (threadIdx.x < 32) {
        float t = 0.0f;
        #pragma unroll
        for (int i = 0; i < 8; ++i) t += red[i][f];
        float cntf = (float)(e - s);
        cntf = cntf > 1.0f ? cntf : 1.0f;
        float p = (t / cntf) * Wl[f];
        #pragma unroll
        for (int off = 16; off > 0; off >>= 1) p += __shfl_down(p, off, 32);
        if (f == 0) out[g] = 1.0f / (1.0f + expf(-(p + bl[0])));
    }
}

// ---------------------------------------------------------------------------
extern "C" void kernel_launch(void* const* d_in, const int* in_sizes, int n_in,
                              void* d_out, int out_size, void* d_ws, size_t ws_size,
                              hipStream_t stream) {
    const float* x     = (const float*)d_in[0];
    const int*   ei    = (const int*)d_in[1];
    const float* ew    = (const float*)d_in[2];
    const int*   batch = (const int*)d_in[3];
    const float* W1 = (const float*)d_in[4];
    const float* g1 = (const float*)d_in[6];
    const float* be1 = (const float*)d_in[7];
    const float* W2 = (const float*)d_in[8];
    const float* g2 = (const float*)d_in[10];
    const float* be2 = (const float*)d_in[11];
    const float* W3 = (const float*)d_in[12];
    const float* g3 = (const float*)d_in[14];
    const float* be3 = (const float*)d_in[15];
    const float* W4 = (const float*)d_in[16];
    const float* g4 = (const float*)d_in[18];
    const float* be4 = (const float*)d_in[19];
    const float* Wl = (const float*)d_in[20];
    const float* bl = (const float*)d_in[21];
    float* out = (float*)d_out;

    char* ws = (char*)d_ws;
    size_t off = 0;
    auto alloc = [&](size_t bytes) -> void* {
        void* p = ws + off;
        off += (bytes + 255) & ~(size_t)255;
        return p;
    };
    // zeroed region first (one memset): cnt64
    u64* cnt64 = (u64*)alloc((size_t)NN * 8);
    const size_t zero_bytes = off;
    // non-zeroed
    float* ac     = (float*)alloc(512 * 4);
    float* P      = (float*)alloc((size_t)256 * SP128 * 4);   // BN partials (max)
    int*   gstart = (int*)  alloc((NG + 1) * 4);
    int*   rowptr = (int*)  alloc((size_t)(NN + 1) * 4);
    int*   bsum   = (int*)  alloc((size_t)SCB * 4);
    float* dis    = (float*)alloc((size_t)NN * 4);
    u32*   ord    = (u32*)  alloc((size_t)NT * 4);
    u64*   edges  = (u64*)  alloc((size_t)NT * 8);
    u16*   xb     = (u16*)  alloc((size_t)NNP * 128 * 2);
    u16*   wt1    = (u16*)  alloc((size_t)256 * 128 * 2);
    u16*   wt2    = (u16*)  alloc((size_t)128 * 256 * 2);
    u16*   wt3    = (u16*)  alloc((size_t)64 * 128 * 2);
    u16*   wt4    = (u16*)  alloc((size_t)32 * 64 * 2);
    u16*   bufA   = (u16*)  alloc((size_t)NNP * 256 * 2);
    u16*   bufB   = (u16*)  alloc((size_t)NNP * 256 * 2);

    hipMemsetAsync(d_ws, 0, zero_bytes, stream);

    // graph build + input prep (merged, overlapping; deg blocks first)
    k_deg_prep<<<EGRID + PREPB, 256, 0, stream>>>(ei, ew, cnt64, ord, x, xb,
                                                  W1, W2, W3, W4, wt1, wt2, wt3, wt4);
    k_scan_a<<<SCB, 256, 0, stream>>>(cnt64, bsum, dis);
    k_scan_c<<<SCB, 256, 0, stream>>>(cnt64, bsum, rowptr, ei, batch, gstart);
    k_csr2<<<EGRID, 256, 0, stream>>>(ei, ew, dis, rowptr, ord, edges);

    // ---- layer 1: aggregate(128) -> GEMM 128->256 (+stats) -> red
    k_spmm_bf<128, false, SP128><<<SP128, 256, 0, stream>>>(rowptr, edges, xb, bufA, P);
    k_gemm_bf<128, 128, false, true><<<dim3(MG, 2), 256, 0, stream>>>(bufA, wt1, bufB, ac, P, NN, 256);
    k_red_g1<<<256, 256, 0, stream>>>(P, g1, be1, ac);

    // ---- layer 2: GEMM 256->128 (BN1 in) -> aggregate(128) (+stats) -> red
    k_gemm_bf<256, 64, true, false><<<dim3(MG, 2), 256, 0, stream>>>(bufB, wt2, bufA, ac, P, NN, 128);
    k_spmm_bf<128, true, SP128><<<SP128, 256, 0, stream>>>(rowptr, edges, bufA, bufB, P);
    k_red_par<128, SP128><<<128, 256, 0, stream>>>(P, g2, be2, ac);

    // ---- layer 3: GEMM 128->64 (BN2 in) -> aggregate(64) (+stats) -> red
    k_gemm_bf<128, 64, true, false><<<dim3(MG, 1), 256, 0, stream>>>(bufB, wt3, bufA, ac, P, NN, 64);
    k_spmm_bf<64, true, SP64><<<SP64, 256, 0, stream>>>(rowptr, edges, bufA, bufB, P);
    k_red_par<64, SP64><<<64, 256, 0, stream>>>(P, g3, be3, ac);

    // ---- layer 4: GEMM 64->32 (BN3 in) -> aggregate(32) (+stats) -> red
    k_gemm_bf<64, 32, true, false><<<dim3(MG, 1), 256, 0, stream>>>(bufB, wt4, bufA, ac, P, NN, 32);
    k_spmm_bf<32, true, SP32><<<SP32, 256, 0, stream>>>(rowptr, edges, bufA, bufB, P);
    k_red_par<32, SP32><<<32, 256, 0, stream>>>(P, g4, be4, ac);

    // ---- fused BN4 + pool + head
    k_pool_bf<<<NG, 256, 0, stream>>>(bufB, gstart, ac, Wl, bl, out);
}